// Round 7
// baseline (243.599 us; speedup 1.0000x reference)
//
#include <hip/hip_runtime.h>

#define BATCH 1024
#define SEQ   200
#define EMB   128
#define VOCAB 100000

typedef __attribute__((ext_vector_type(8))) short short8;
typedef __attribute__((ext_vector_type(4))) float f32x4;
typedef _Float16 hh2 __attribute__((ext_vector_type(2)));

__device__ __forceinline__ unsigned short f2bf(float x) {
  unsigned u = __float_as_uint(x);
  u += 0x7fffu + ((u >> 16) & 1u);   // RNE
  return (unsigned short)(u >> 16);
}
__device__ __forceinline__ float bf2f(unsigned short b) {
  return __uint_as_float(((unsigned)b) << 16);
}

// ---------------------------------------------------------------------------
// cvt: Win (fp32) -> bf16, once. 16384 elements.
// ---------------------------------------------------------------------------
__global__ void cvt_bf16(const float* __restrict__ src,
                         unsigned short* __restrict__ dst, int n) {
  int i = blockIdx.x * 256 + threadIdx.x;
  if (i < n) dst[i] = f2bf(src[i]);
}

// ---------------------------------------------------------------------------
// Phase 1 (VERIFIED r2/r6-compile): ip[r][f] = sum_e emb[x[r]][e]*Win[f][e],
// bf16 out. r = b*SEQ + s. 1600 blocks x 256 thr.
// ---------------------------------------------------------------------------
__global__ __launch_bounds__(256) void proj2(
    const int* __restrict__ xidx, const float* __restrict__ emb,
    const unsigned short* __restrict__ Wb, unsigned short* __restrict__ ip)
{
  const int tid = threadIdx.x;
  const int w   = tid >> 6;
  const int l   = tid & 63;
  const int l15 = l & 15;
  const int lhi = l >> 4;

  short8 bfrag[8][4];
#pragma unroll
  for (int nt = 0; nt < 8; ++nt)
#pragma unroll
    for (int kc = 0; kc < 4; ++kc)
      bfrag[nt][kc] = *(const short8*)(Wb + (nt*16 + l15)*EMB + kc*32 + lhi*8);

#pragma unroll
  for (int t = 0; t < 2; ++t) {
    const int m  = blockIdx.x*8 + w*2 + t;
    const int rb = m * 16;
    const long xe = (long)xidx[rb + l15] * EMB;
    short8 afrag[4];
#pragma unroll
    for (int kc = 0; kc < 4; ++kc) {
      const float4* p = (const float4*)(emb + xe + kc*32 + lhi*8);
      float4 a = p[0], b = p[1];
      short8 fr;
      fr[0]=(short)f2bf(a.x); fr[1]=(short)f2bf(a.y);
      fr[2]=(short)f2bf(a.z); fr[3]=(short)f2bf(a.w);
      fr[4]=(short)f2bf(b.x); fr[5]=(short)f2bf(b.y);
      fr[6]=(short)f2bf(b.z); fr[7]=(short)f2bf(b.w);
      afrag[kc] = fr;
    }
    f32x4 acc[8];
#pragma unroll
    for (int nt = 0; nt < 8; ++nt) acc[nt] = (f32x4)(0.0f);
#pragma unroll
    for (int kc = 0; kc < 4; ++kc)
#pragma unroll
      for (int nt = 0; nt < 8; ++nt)
        acc[nt] = __builtin_amdgcn_mfma_f32_16x16x32_bf16(afrag[kc], bfrag[nt][kc], acc[nt], 0, 0, 0);
#pragma unroll
    for (int nt = 0; nt < 8; ++nt)
#pragma unroll
      for (int j = 0; j < 4; ++j)
        ip[(long)(rb + lhi*4 + j)*EMB + nt*16 + l15] = f2bf(acc[nt][j]);
  }
}

// ---------------------------------------------------------------------------
// Phase 2: rnn7 — all-VALU fdot2(f16) recurrence. 512 blocks x 128 thr
// (2 waves); wave = batch row (blockIdx*2 + w); lane l owns f = 2l, 2l+1.
// h stored as fp16 PAIRS (RNE) in LDS, double-buffered; weights Wh rows as
// fp16 pairs in 128 VGPRs. Per step: 16 broadcast ds_read_b128 + 128
// __builtin_amdgcn_fdot2 (fp32 accum, 8 indep chains) + 2 tanh + 1 uint
// h-write + raw lgkmcnt barrier. ip (bf16, from proj2) prefetched 2 deep;
// vmcnt never drained. No inline-asm math (r6 post-mortem: raw-asm
// v_dot2_f32_bf16 produced 3.5e-2 absmax; builtin path de-risks encoding).
// ---------------------------------------------------------------------------
__global__ __launch_bounds__(128, 1) void rnn7(
    const unsigned short* __restrict__ ip, const float* __restrict__ Wh,
    const float* __restrict__ bin, const float* __restrict__ bh,
    float* __restrict__ out)
{
  __shared__ unsigned int hbuf[2][2][64];   // [buf][row][64 uints = 128 f16]

  const int tid = threadIdx.x;
  const int w   = tid >> 6;            // wave = local row 0..1
  const int l   = tid & 63;
  const int row = blockIdx.x*2 + w;    // global batch row
  const int f0  = 2*l;
  const int f1  = 2*l + 1;

  // weights: w0[p] = {Wh[f0][2p], Wh[f0][2p+1]} fp16 RNE; same for w1/f1.
  hh2 w0[64], w1[64];
#pragma unroll
  for (int q = 0; q < 32; ++q) {
    float4 a = ((const float4*)(Wh + (size_t)f0*EMB))[q];
    w0[2*q]   = (hh2){(_Float16)a.x, (_Float16)a.y};
    w0[2*q+1] = (hh2){(_Float16)a.z, (_Float16)a.w};
    float4 b = ((const float4*)(Wh + (size_t)f1*EMB))[q];
    w1[2*q]   = (hh2){(_Float16)b.x, (_Float16)b.y};
    w1[2*q+1] = (hh2){(_Float16)b.z, (_Float16)b.w};
  }
  const float bias0 = bin[f0] + bh[f0];
  const float bias1 = bin[f1] + bh[f1];

  // zero h buffer 0 (128 uints over 128 threads)
  hbuf[0][w][l] = 0u;
  __syncthreads();   // prologue full drain OK (once)

  // ip stream: uint = {ip[row][s][2l], ip[row][s][2l+1]}; prefetch 2 deep
  const unsigned int* ipp = (const unsigned int*)(ip + (size_t)row * SEQ * EMB) + l;
  unsigned int ic = ipp[0];                 // s = 0
  unsigned int in = ipp[EMB/2];             // s = 1  (EMB/2 uints per row)

  float hf0 = 0.0f, hf1 = 0.0f;

  for (int s = 0; s < SEQ; ++s) {
    // issue ip load for s+2 (stays in flight across the raw barrier)
    const int sp = (s + 2 < SEQ) ? s + 2 : SEQ - 1;
    const unsigned int pn = ipp[(size_t)sp * (EMB/2)];

    // broadcast-read this row's h (256B = 16 x b128, all lanes same addr)
    const uint4* th = (const uint4*)&hbuf[s & 1][w][0];

    // accum chains: 4 per output (indexed by chunk&3, fully unrolled)
    float a0[4], a1[4];
    a0[0] = bias0 + __uint_as_float(ic << 16);           // low bf16 of ip
    a1[0] = bias1 + __uint_as_float(ic & 0xffff0000u);   // high bf16 of ip
    a0[1] = a0[2] = a0[3] = 0.0f;
    a1[1] = a1[2] = a1[3] = 0.0f;

#pragma unroll
    for (int c = 0; c < 16; ++c) {
      const uint4 hc = th[c];
      const hh2 hx = __builtin_bit_cast(hh2, hc.x);   // e = 8c+0,1
      const hh2 hy = __builtin_bit_cast(hh2, hc.y);   // e = 8c+2,3
      const hh2 hz = __builtin_bit_cast(hh2, hc.z);   // e = 8c+4,5
      const hh2 hw = __builtin_bit_cast(hh2, hc.w);   // e = 8c+6,7
      const int k = c & 3;
      a0[k] = __builtin_amdgcn_fdot2(hx, w0[4*c+0], a0[k], false);
      a0[k] = __builtin_amdgcn_fdot2(hy, w0[4*c+1], a0[k], false);
      a0[k] = __builtin_amdgcn_fdot2(hz, w0[4*c+2], a0[k], false);
      a0[k] = __builtin_amdgcn_fdot2(hw, w0[4*c+3], a0[k], false);
      a1[k] = __builtin_amdgcn_fdot2(hx, w1[4*c+0], a1[k], false);
      a1[k] = __builtin_amdgcn_fdot2(hy, w1[4*c+1], a1[k], false);
      a1[k] = __builtin_amdgcn_fdot2(hz, w1[4*c+2], a1[k], false);
      a1[k] = __builtin_amdgcn_fdot2(hw, w1[4*c+3], a1[k], false);
    }
    const float v0 = (a0[0] + a0[1]) + (a0[2] + a0[3]);
    const float v1 = (a1[0] + a1[1]) + (a1[2] + a1[3]);

    // tanh (proven path)
    const float e0 = __expf(2.0f * v0);
    hf0 = 1.0f - __fdividef(2.0f, e0 + 1.0f);
    const float e1 = __expf(2.0f * v1);
    hf1 = 1.0f - __fdividef(2.0f, e1 + 1.0f);

    // write next h as fp16 pair (RNE scalar cvt), one uint, conflict-free
    const hh2 hp = (hh2){(_Float16)hf0, (_Float16)hf1};
    hbuf[(s + 1) & 1][w][l] = __builtin_bit_cast(unsigned int, hp);

    // rotate ip pipeline
    ic = in;
    in = pn;

    // own LDS ops retired + barrier; vmcnt (ip prefetch) stays in flight
    asm volatile("s_waitcnt lgkmcnt(0)\n\ts_barrier" ::: "memory");
  }

  // L2 normalize: whole row in this wave (2 values/lane)
  float pj = hf0*hf0 + hf1*hf1;
#pragma unroll
  for (int off = 1; off < 64; off <<= 1) pj += __shfl_xor(pj, off, 64);
  const float inv = 1.0f / fmaxf(sqrtf(pj), 1e-12f);
  float2 o;
  o.x = hf0 * inv;
  o.y = hf1 * inv;
  *(float2*)(out + (size_t)row*EMB + f0) = o;
}

// ---------------------------------------------------------------------------
// Fallback (small ws): round-1 VALU recurrence (known-correct, no scratch).
// ---------------------------------------------------------------------------
__global__ __launch_bounds__(512) void rnn_fused(
    const int* __restrict__ xidx, const float* __restrict__ emb,
    const float* __restrict__ Win, const float* __restrict__ bin,
    const float* __restrict__ Wh,  const float* __restrict__ bh,
    float* __restrict__ out)
{
  __shared__ float h_lds[4][EMB];
  __shared__ float part[8][4][EMB];
  __shared__ float emb_lds[2][4][EMB];
  __shared__ int   x_lds[4][SEQ];
  __shared__ float red[8];

  const int t   = threadIdx.x;
  const int f0  = (t & 63) * 2;
  const int eg  = t >> 6;
  const int e0  = eg * 16;
  const int b0  = blockIdx.x * 4;
  const int row = t >> 7;
  const int ff  = t & 127;

  float wh0[16], wh1[16], wi0[16], wi1[16];
  {
    const float* p0 = Wh + f0*EMB + e0;
    const float* p1 = Wh + (f0+1)*EMB + e0;
    const float* q0 = Win + f0*EMB + e0;
    const float* q1 = Win + (f0+1)*EMB + e0;
#pragma unroll
    for (int q = 0; q < 4; ++q) {
      float4 a = ((const float4*)p0)[q];
      wh0[4*q+0]=a.x; wh0[4*q+1]=a.y; wh0[4*q+2]=a.z; wh0[4*q+3]=a.w;
      float4 b = ((const float4*)p1)[q];
      wh1[4*q+0]=b.x; wh1[4*q+1]=b.y; wh1[4*q+2]=b.z; wh1[4*q+3]=b.w;
      float4 c = ((const float4*)q0)[q];
      wi0[4*q+0]=c.x; wi0[4*q+1]=c.y; wi0[4*q+2]=c.z; wi0[4*q+3]=c.w;
      float4 d = ((const float4*)q1)[q];
      wi1[4*q+0]=d.x; wi1[4*q+1]=d.y; wi1[4*q+2]=d.z; wi1[4*q+3]=d.w;
    }
  }
  const float bc = bin[ff] + bh[ff];
  h_lds[row][ff] = 0.0f;
  for (int i = t; i < 4*SEQ; i += 512)
    x_lds[i / SEQ][i % SEQ] = xidx[(b0 + i/SEQ)*SEQ + (i % SEQ)];
  __syncthreads();
  emb_lds[0][row][ff] = emb[(long)x_lds[row][0]*EMB + ff];
  __syncthreads();

  int cur = 0;
  for (int s = 0; s < SEQ; ++s) {
    float nxt = 0.0f;
    if (s + 1 < SEQ) nxt = emb[(long)x_lds[row][s+1]*EMB + ff];
    float pa0[4], pa1[4];
#pragma unroll
    for (int rq = 0; rq < 4; ++rq) { pa0[rq] = 0.0f; pa1[rq] = 0.0f; }
#pragma unroll
    for (int rq = 0; rq < 4; ++rq) {
      const float4* hp  = (const float4*)&h_lds[rq][e0];
      const float4* epv = (const float4*)&emb_lds[cur][rq][e0];
#pragma unroll
      for (int q = 0; q < 4; ++q) {
        float4 hv = hp[q], ev = epv[q];
        pa0[rq] = fmaf(hv.x, wh0[4*q+0], pa0[rq]); pa0[rq] = fmaf(hv.y, wh0[4*q+1], pa0[rq]);
        pa0[rq] = fmaf(hv.z, wh0[4*q+2], pa0[rq]); pa0[rq] = fmaf(hv.w, wh0[4*q+3], pa0[rq]);
        pa1[rq] = fmaf(hv.x, wh1[4*q+0], pa1[rq]); pa1[rq] = fmaf(hv.y, wh1[4*q+1], pa1[rq]);
        pa1[rq] = fmaf(hv.z, wh1[4*q+2], pa1[rq]); pa1[rq] = fmaf(hv.w, wh1[4*q+3], pa1[rq]);
        pa0[rq] = fmaf(ev.x, wi0[4*q+0], pa0[rq]); pa0[rq] = fmaf(ev.y, wi0[4*q+1], pa0[rq]);
        pa0[rq] = fmaf(ev.z, wi0[4*q+2], pa0[rq]); pa0[rq] = fmaf(ev.w, wi0[4*q+3], pa0[rq]);
        pa1[rq] = fmaf(ev.x, wi1[4*q+0], pa1[rq]); pa1[rq] = fmaf(ev.y, wi1[4*q+1], pa1[rq]);
        pa1[rq] = fmaf(ev.z, wi1[4*q+2], pa1[rq]); pa1[rq] = fmaf(ev.w, wi1[4*q+3], pa1[rq]);
      }
    }
#pragma unroll
    for (int rq = 0; rq < 4; ++rq) {
      part[eg][rq][f0]   = pa0[rq];
      part[eg][rq][f0+1] = pa1[rq];
    }
    __syncthreads();
    float acc = bc;
#pragma unroll
    for (int g = 0; g < 8; ++g) acc += part[g][row][ff];
    float hn = tanhf(acc);
    if (s + 1 < SEQ) emb_lds[cur ^ 1][row][ff] = nxt;
    h_lds[row][ff] = hn;
    __syncthreads();
    cur ^= 1;
  }
  float hv = h_lds[row][ff];
  float sq = hv * hv;
#pragma unroll
  for (int off = 32; off > 0; off >>= 1) sq += __shfl_xor(sq, off, 64);
  if ((t & 63) == 0) red[t >> 6] = sq;
  __syncthreads();
  float nrm = sqrtf(red[row*2] + red[row*2 + 1]);
  out[(b0 + row)*EMB + ff] = hv / fmaxf(nrm, 1e-12f);
}

// ---------------------------------------------------------------------------
extern "C" void kernel_launch(void* const* d_in, const int* in_sizes, int n_in,
                              void* d_out, int out_size, void* d_ws, size_t ws_size,
                              hipStream_t stream) {
  const int*   x    = (const int*)  d_in[0];
  const float* emb  = (const float*)d_in[1];
  const float* Win  = (const float*)d_in[2];
  const float* bin  = (const float*)d_in[3];
  const float* Wh   = (const float*)d_in[4];
  const float* bh   = (const float*)d_in[5];
  float* out = (float*)d_out;

  const size_t ip_bytes = (size_t)BATCH * SEQ * EMB * sizeof(unsigned short); // 52.4 MB
  const size_t need     = ip_bytes + EMB*EMB*sizeof(unsigned short);
  if (ws_size >= need) {
    unsigned short* ip = (unsigned short*)d_ws;
    unsigned short* Wb = (unsigned short*)((char*)d_ws + ip_bytes);
    cvt_bf16<<<(EMB*EMB + 255)/256, 256, 0, stream>>>(Win, Wb, EMB*EMB);
    proj2<<<(BATCH*SEQ)/128, 256, 0, stream>>>(x, emb, Wb, ip);
    rnn7<<<BATCH/2, 128, 0, stream>>>(ip, Wh, bin, bh, out);
  } else {
    rnn_fused<<<BATCH/4, 512, 0, stream>>>(x, emb, Win, bin, Wh, bh, out);
  }
}

// Round 8
// 151.912 us; speedup vs baseline: 1.6036x; 1.6036x over previous
//
#include <hip/hip_runtime.h>

#define BATCH 1024
#define SEQ   200
#define EMB   128
#define VOCAB 100000

typedef __attribute__((ext_vector_type(8))) short short8;
typedef __attribute__((ext_vector_type(4))) float f32x4;
typedef _Float16 hh2 __attribute__((ext_vector_type(2)));

__device__ __forceinline__ unsigned short f2bf(float x) {
  unsigned u = __float_as_uint(x);
  u += 0x7fffu + ((u >> 16) & 1u);   // RNE
  return (unsigned short)(u >> 16);
}
__device__ __forceinline__ float bf2f(unsigned short b) {
  return __uint_as_float(((unsigned)b) << 16);
}

// ---------------------------------------------------------------------------
// cvt: Win (fp32) -> bf16, once. 16384 elements.
// ---------------------------------------------------------------------------
__global__ void cvt_bf16(const float* __restrict__ src,
                         unsigned short* __restrict__ dst, int n) {
  int i = blockIdx.x * 256 + threadIdx.x;
  if (i < n) dst[i] = f2bf(src[i]);
}

// ---------------------------------------------------------------------------
// cvt_wh: Wh (fp32 [128][128]) -> W2t (uint [64][128]), once.
// W2t[j*128 + f] = pack{ fp16(Wh[f][j]), fp16(Wh[f][j+64]) }.
// Gives rnn8 fully-coalesced weight loads: lane l reads W2t[j*128 + l].
// ---------------------------------------------------------------------------
__global__ __launch_bounds__(256) void cvt_wh(const float* __restrict__ Wh,
                                              unsigned int* __restrict__ W2t) {
  const int idx = blockIdx.x * 256 + threadIdx.x;   // 8192 total
  const int j = idx >> 7;
  const int f = idx & 127;
  const hh2 p = (hh2){(_Float16)Wh[f*EMB + j], (_Float16)Wh[f*EMB + j + 64]};
  W2t[idx] = __builtin_bit_cast(unsigned int, p);
}

// ---------------------------------------------------------------------------
// Phase 1 (r2-verified MFMA core): input projection, now storing PAIRED bf16:
// ipP[r*64 + q] = { bf16(ip[r][q]) , bf16(ip[r][q+64]) }  (lo,hi in one uint)
// r = b*SEQ + s. 1600 blocks x 256 thr; block covers 128 rows.
// ---------------------------------------------------------------------------
__global__ __launch_bounds__(256) void proj2(
    const int* __restrict__ xidx, const float* __restrict__ emb,
    const unsigned short* __restrict__ Wb, unsigned int* __restrict__ ipP)
{
  const int tid = threadIdx.x;
  const int w   = tid >> 6;
  const int l   = tid & 63;
  const int l15 = l & 15;
  const int lhi = l >> 4;

  short8 bfrag[8][4];
#pragma unroll
  for (int nt = 0; nt < 8; ++nt)
#pragma unroll
    for (int kc = 0; kc < 4; ++kc)
      bfrag[nt][kc] = *(const short8*)(Wb + (nt*16 + l15)*EMB + kc*32 + lhi*8);

#pragma unroll
  for (int t = 0; t < 2; ++t) {
    const int m  = blockIdx.x*8 + w*2 + t;
    const int rb = m * 16;
    const long xe = (long)xidx[rb + l15] * EMB;
    short8 afrag[4];
#pragma unroll
    for (int kc = 0; kc < 4; ++kc) {
      const float4* p = (const float4*)(emb + xe + kc*32 + lhi*8);
      float4 a = p[0], b = p[1];
      short8 fr;
      fr[0]=(short)f2bf(a.x); fr[1]=(short)f2bf(a.y);
      fr[2]=(short)f2bf(a.z); fr[3]=(short)f2bf(a.w);
      fr[4]=(short)f2bf(b.x); fr[5]=(short)f2bf(b.y);
      fr[6]=(short)f2bf(b.z); fr[7]=(short)f2bf(b.w);
      afrag[kc] = fr;
    }
    f32x4 acc[8];
#pragma unroll
    for (int nt = 0; nt < 8; ++nt) acc[nt] = (f32x4)(0.0f);
#pragma unroll
    for (int kc = 0; kc < 4; ++kc)
#pragma unroll
      for (int nt = 0; nt < 8; ++nt)
        acc[nt] = __builtin_amdgcn_mfma_f32_16x16x32_bf16(afrag[kc], bfrag[nt][kc], acc[nt], 0, 0, 0);
    // D layout: col=l15 (batch row), row=lhi*4+j (f). Pair f with f+64.
#pragma unroll
    for (int nt = 0; nt < 4; ++nt)
#pragma unroll
      for (int j = 0; j < 4; ++j) {
        const unsigned int u = (unsigned)f2bf(acc[nt][j])
                             | ((unsigned)f2bf(acc[nt+4][j]) << 16);
        ipP[(long)(rb + lhi*4 + j)*64 + nt*16 + l15] = u;
      }
  }
}

// ---------------------------------------------------------------------------
// Phase 2: rnn8 — barrier-free wave-per-row recurrence. 256 blocks x 256 thr
// (4 waves); wave = batch row (1024 waves = 1/SIMD over all 256 CUs).
// Lane l owns f = {l, l+64}. h stored as fp16 pairs {h[j],h[j+64]} (1 uint/
// lane) in per-wave LDS double-buffer. Per step: 1 ds_write_b32 + 16
// broadcast ds_read_b128 (intra-wave RAW; per-wave DS ordering + compiler
// lgkmcnt — NO barrier) + 128 fdot2 (8 fp32 chains) + 2 tanh + 1 uint ip
// load (2-step prefetch, vmcnt in flight). Weights: 128 uints/lane from
// coalesced W2t; launch_bounds(256,1) -> 512-VGPR budget, no spill pressure.
// ---------------------------------------------------------------------------
__global__ __launch_bounds__(256, 1) void rnn8(
    const unsigned int* __restrict__ ipP, const unsigned int* __restrict__ W2t,
    const float* __restrict__ bin, const float* __restrict__ bh,
    float* __restrict__ out)
{
  __shared__ unsigned int hb[4][2][64];   // [wave][buf][64 uints = h pairs]

  const int tid = threadIdx.x;
  const int w   = tid >> 6;            // wave = local row 0..3
  const int l   = tid & 63;
  const int row = blockIdx.x*4 + w;    // global batch row

  // weights: w0[j] = {Wh[l][j], Wh[l][j+64]}, w1[j] = {Wh[l+64][j], Wh[l+64][j+64]}
  unsigned int w0[64], w1[64];
#pragma unroll
  for (int j = 0; j < 64; ++j) {
    w0[j] = W2t[j*128 + l];
    w1[j] = W2t[j*128 + 64 + l];
  }
  const float bias0 = bin[l]      + bh[l];
  const float bias1 = bin[l + 64] + bh[l + 64];

  // h_0 = 0
  hb[w][0][l] = 0u;

  // ip stream: uint pair {ip[row][s][l], ip[row][s][l+64]}; prefetch 2 deep
  const unsigned int* ipp = ipP + (size_t)row * SEQ * 64 + l;
  unsigned int ic = ipp[0];
  unsigned int in = ipp[64];

  float hf0 = 0.0f, hf1 = 0.0f;

  for (int s = 0; s < SEQ; ++s) {
    // issue ip load for s+2 (stays in flight; compiler counts vmcnt)
    const int sp = (s + 2 < SEQ) ? s + 2 : SEQ - 1;
    const unsigned int pn = ipp[(size_t)sp * 64];

    // broadcast-read this wave's h (256B = 16 x b128, all lanes same addr)
    const uint4* th = (const uint4*)&hb[w][s & 1][0];

    float a0[4], a1[4];
    a0[0] = bias0 + __uint_as_float(ic << 16);
    a1[0] = bias1 + __uint_as_float(ic & 0xffff0000u);
    a0[1] = a0[2] = a0[3] = 0.0f;
    a1[1] = a1[2] = a1[3] = 0.0f;

#pragma unroll
    for (int c = 0; c < 16; ++c) {
      const uint4 hc = th[c];
      const hh2 hx = __builtin_bit_cast(hh2, hc.x);   // pairs j=4c+0
      const hh2 hy = __builtin_bit_cast(hh2, hc.y);   //       j=4c+1
      const hh2 hz = __builtin_bit_cast(hh2, hc.z);   //       j=4c+2
      const hh2 hw = __builtin_bit_cast(hh2, hc.w);   //       j=4c+3
      const int k = c & 3;
      a0[k] = __builtin_amdgcn_fdot2(hx, __builtin_bit_cast(hh2, w0[4*c+0]), a0[k], false);
      a0[k] = __builtin_amdgcn_fdot2(hy, __builtin_bit_cast(hh2, w0[4*c+1]), a0[k], false);
      a0[k] = __builtin_amdgcn_fdot2(hz, __builtin_bit_cast(hh2, w0[4*c+2]), a0[k], false);
      a0[k] = __builtin_amdgcn_fdot2(hw, __builtin_bit_cast(hh2, w0[4*c+3]), a0[k], false);
      a1[k] = __builtin_amdgcn_fdot2(hx, __builtin_bit_cast(hh2, w1[4*c+0]), a1[k], false);
      a1[k] = __builtin_amdgcn_fdot2(hy, __builtin_bit_cast(hh2, w1[4*c+1]), a1[k], false);
      a1[k] = __builtin_amdgcn_fdot2(hz, __builtin_bit_cast(hh2, w1[4*c+2]), a1[k], false);
      a1[k] = __builtin_amdgcn_fdot2(hw, __builtin_bit_cast(hh2, w1[4*c+3]), a1[k], false);
    }
    const float v0 = (a0[0] + a0[1]) + (a0[2] + a0[3]);
    const float v1 = (a1[0] + a1[1]) + (a1[2] + a1[3]);

    // tanh (proven path)
    const float e0 = __expf(2.0f * v0);
    hf0 = 1.0f - __fdividef(2.0f, e0 + 1.0f);
    const float e1 = __expf(2.0f * v1);
    hf1 = 1.0f - __fdividef(2.0f, e1 + 1.0f);

    // write next h pair (fp16 RNE), one uint per lane, conflict-free.
    // Intra-wave RAW on LDS: per-wave DS ops are ordered; compiler inserts
    // the lgkmcnt before next iteration's reads. No barrier needed.
    const hh2 hp = (hh2){(_Float16)hf0, (_Float16)hf1};
    hb[w][(s + 1) & 1][l] = __builtin_bit_cast(unsigned int, hp);

    ic = in;
    in = pn;
  }

  // L2 normalize: whole row in this wave (2 values/lane)
  float pj = hf0*hf0 + hf1*hf1;
#pragma unroll
  for (int off = 1; off < 64; off <<= 1) pj += __shfl_xor(pj, off, 64);
  const float inv = 1.0f / fmaxf(sqrtf(pj), 1e-12f);
  out[(size_t)row*EMB + l]      = hf0 * inv;
  out[(size_t)row*EMB + 64 + l] = hf1 * inv;
}

// ---------------------------------------------------------------------------
// Fallback (small ws): round-1 VALU recurrence (known-correct, no scratch).
// ---------------------------------------------------------------------------
__global__ __launch_bounds__(512) void rnn_fused(
    const int* __restrict__ xidx, const float* __restrict__ emb,
    const float* __restrict__ Win, const float* __restrict__ bin,
    const float* __restrict__ Wh,  const float* __restrict__ bh,
    float* __restrict__ out)
{
  __shared__ float h_lds[4][EMB];
  __shared__ float part[8][4][EMB];
  __shared__ float emb_lds[2][4][EMB];
  __shared__ int   x_lds[4][SEQ];
  __shared__ float red[8];

  const int t   = threadIdx.x;
  const int f0  = (t & 63) * 2;
  const int eg  = t >> 6;
  const int e0  = eg * 16;
  const int b0  = blockIdx.x * 4;
  const int row = t >> 7;
  const int ff  = t & 127;

  float wh0[16], wh1[16], wi0[16], wi1[16];
  {
    const float* p0 = Wh + f0*EMB + e0;
    const float* p1 = Wh + (f0+1)*EMB + e0;
    const float* q0 = Win + f0*EMB + e0;
    const float* q1 = Win + (f0+1)*EMB + e0;
#pragma unroll
    for (int q = 0; q < 4; ++q) {
      float4 a = ((const float4*)p0)[q];
      wh0[4*q+0]=a.x; wh0[4*q+1]=a.y; wh0[4*q+2]=a.z; wh0[4*q+3]=a.w;
      float4 b = ((const float4*)p1)[q];
      wh1[4*q+0]=b.x; wh1[4*q+1]=b.y; wh1[4*q+2]=b.z; wh1[4*q+3]=b.w;
      float4 c = ((const float4*)q0)[q];
      wi0[4*q+0]=c.x; wi0[4*q+1]=c.y; wi0[4*q+2]=c.z; wi0[4*q+3]=c.w;
      float4 d = ((const float4*)q1)[q];
      wi1[4*q+0]=d.x; wi1[4*q+1]=d.y; wi1[4*q+2]=d.z; wi1[4*q+3]=d.w;
    }
  }
  const float bc = bin[ff] + bh[ff];
  h_lds[row][ff] = 0.0f;
  for (int i = t; i < 4*SEQ; i += 512)
    x_lds[i / SEQ][i % SEQ] = xidx[(b0 + i/SEQ)*SEQ + (i % SEQ)];
  __syncthreads();
  emb_lds[0][row][ff] = emb[(long)x_lds[row][0]*EMB + ff];
  __syncthreads();

  int cur = 0;
  for (int s = 0; s < SEQ; ++s) {
    float nxt = 0.0f;
    if (s + 1 < SEQ) nxt = emb[(long)x_lds[row][s+1]*EMB + ff];
    float pa0[4], pa1[4];
#pragma unroll
    for (int rq = 0; rq < 4; ++rq) { pa0[rq] = 0.0f; pa1[rq] = 0.0f; }
#pragma unroll
    for (int rq = 0; rq < 4; ++rq) {
      const float4* hp  = (const float4*)&h_lds[rq][e0];
      const float4* epv = (const float4*)&emb_lds[cur][rq][e0];
#pragma unroll
      for (int q = 0; q < 4; ++q) {
        float4 hv = hp[q], ev = epv[q];
        pa0[rq] = fmaf(hv.x, wh0[4*q+0], pa0[rq]); pa0[rq] = fmaf(hv.y, wh0[4*q+1], pa0[rq]);
        pa0[rq] = fmaf(hv.z, wh0[4*q+2], pa0[rq]); pa0[rq] = fmaf(hv.w, wh0[4*q+3], pa0[rq]);
        pa1[rq] = fmaf(hv.x, wh1[4*q+0], pa1[rq]); pa1[rq] = fmaf(hv.y, wh1[4*q+1], pa1[rq]);
        pa1[rq] = fmaf(hv.z, wh1[4*q+2], pa1[rq]); pa1[rq] = fmaf(hv.w, wh1[4*q+3], pa1[rq]);
        pa0[rq] = fmaf(ev.x, wi0[4*q+0], pa0[rq]); pa0[rq] = fmaf(ev.y, wi0[4*q+1], pa0[rq]);
        pa0[rq] = fmaf(ev.z, wi0[4*q+2], pa0[rq]); pa0[rq] = fmaf(ev.w, wi0[4*q+3], pa0[rq]);
        pa1[rq] = fmaf(ev.x, wi1[4*q+0], pa1[rq]); pa1[rq] = fmaf(ev.y, wi1[4*q+1], pa1[rq]);
        pa1[rq] = fmaf(ev.z, wi1[4*q+2], pa1[rq]); pa1[rq] = fmaf(ev.w, wi1[4*q+3], pa1[rq]);
      }
    }
#pragma unroll
    for (int rq = 0; rq < 4; ++rq) {
      part[eg][rq][f0]   = pa0[rq];
      part[eg][rq][f0+1] = pa1[rq];
    }
    __syncthreads();
    float acc = bc;
#pragma unroll
    for (int g = 0; g < 8; ++g) acc += part[g][row][ff];
    float hn = tanhf(acc);
    if (s + 1 < SEQ) emb_lds[cur ^ 1][row][ff] = nxt;
    h_lds[row][ff] = hn;
    __syncthreads();
    cur ^= 1;
  }
  float hv = h_lds[row][ff];
  float sq = hv * hv;
#pragma unroll
  for (int off = 32; off > 0; off >>= 1) sq += __shfl_xor(sq, off, 64);
  if ((t & 63) == 0) red[t >> 6] = sq;
  __syncthreads();
  float nrm = sqrtf(red[row*2] + red[row*2 + 1]);
  out[(b0 + row)*EMB + ff] = hv / fmaxf(nrm, 1e-12f);
}

// ---------------------------------------------------------------------------
extern "C" void kernel_launch(void* const* d_in, const int* in_sizes, int n_in,
                              void* d_out, int out_size, void* d_ws, size_t ws_size,
                              hipStream_t stream) {
  const int*   x    = (const int*)  d_in[0];
  const float* emb  = (const float*)d_in[1];
  const float* Win  = (const float*)d_in[2];
  const float* bin  = (const float*)d_in[3];
  const float* Wh   = (const float*)d_in[4];
  const float* bh   = (const float*)d_in[5];
  float* out = (float*)d_out;

  const size_t ip_bytes = (size_t)BATCH * SEQ * 64 * sizeof(unsigned int); // 52.4 MB
  const size_t wb_bytes = (size_t)EMB * EMB * sizeof(unsigned short);      // 32 KB
  const size_t need     = ip_bytes + wb_bytes + 64*128*sizeof(unsigned int);
  if (ws_size >= need) {
    unsigned int*   ipP = (unsigned int*)d_ws;
    unsigned short* Wb  = (unsigned short*)((char*)d_ws + ip_bytes);
    unsigned int*   W2t = (unsigned int*)((char*)d_ws + ip_bytes + wb_bytes);
    cvt_bf16<<<(EMB*EMB + 255)/256, 256, 0, stream>>>(Win, Wb, EMB*EMB);
    cvt_wh<<<(64*128)/256, 256, 0, stream>>>(Wh, W2t);
    proj2<<<(BATCH*SEQ)/128, 256, 0, stream>>>(x, emb, Wb, ipP);
    rnn8<<<BATCH/4, 256, 0, stream>>>(ipP, W2t, bin, bh, out);
  } else {
    rnn_fused<<<BATCH/4, 512, 0, stream>>>(x, emb, Win, bin, Wh, bh, out);
  }
}